// Round 5
// baseline (10130.092 us; speedup 1.0000x reference)
//
#include <hip/hip_runtime.h>

// IJGNN attention-MPNN, 3 iterations — correctness round: fp32 inputs
// (confirmed by probe), fp32 OUTPUTS (reference dtype), bf16 internal storage.

#define GN 25000
#define GE 400000

typedef unsigned short u16;

__device__ inline float b2f(u16 v) {
  union { unsigned int u; float f; } x; x.u = ((unsigned int)v) << 16; return x.f;
}
__device__ inline u16 f2b(float f) {
  union { float f; unsigned int u; } x; x.f = f;
  unsigned int u = x.u;
  u += 0x7fffu + ((u >> 16) & 1u);
  return (u16)(u >> 16);
}

// ---------------- dtype probe (robustness; expected: fp32 -> flag=1) ----------------
__global__ void detect_dtype(const void* nf, int* flag) {
  if (blockIdx.x == 0 && threadIdx.x == 0) {
    const u16* p = (const u16*)nf;
    int cnt = 0;
    for (int i = 0; i < 512; i += 2) {
      int e = (p[i] >> 7) & 0xFF;
      if (e >= 0x70 && e <= 0x85) cnt++;
    }
    *flag = (cnt < 128) ? 1 : 0;
  }
}

__global__ void convert_kernel(const void* src, u16* dst, long n, const int* flag) {
  int f32 = *flag;
  long i = (long)blockIdx.x * blockDim.x + threadIdx.x;
  long stride = (long)gridDim.x * blockDim.x;
  for (; i < n; i += stride)
    dst[i] = f32 ? f2b(((const float*)src)[i]) : ((const u16*)src)[i];
}

// ---------------- weight pre-transpose ----------------
__global__ void prep_weights(const u16* We, const u16* Wn, const u16* Won, const u16* Woe,
                             u16* WeT, u16* WnpT, u16* WnuT, u16* WoN, u16* WoE) {
  int tid = blockIdx.x * blockDim.x + threadIdx.x;
  int nt = gridDim.x * blockDim.x;
  for (int i = tid; i < 128 * 160; i += nt) { int n = i / 160, k = i % 160; WeT[i] = We[(320 + k) * 128 + n]; }
  for (int i = tid; i < 256 * 160; i += nt) {
    int c = i / 160, k = i % 160;
    WnpT[i] = (c < 128) ? We[k * 128 + c] : We[(160 + k) * 128 + (c - 128)];
  }
  for (int i = tid; i < 128 * 288; i += nt) { int c = i / 288, k = i % 288; WnuT[i] = Wn[k * 128 + c]; }
  for (int i = tid; i < 32 * 128; i += nt) {
    int c = i / 128, k = i % 128;
    WoN[i] = Won[k * 32 + c];
    WoE[i] = Woe[k * 32 + c];
  }
}

// ---------------- CSR build (dst buckets) ----------------
__global__ void hist_kernel(const int* dst, int* counts, int n) {
  for (int e = blockIdx.x * blockDim.x + threadIdx.x; e < n; e += gridDim.x * blockDim.x)
    atomicAdd(&counts[dst[e]], 1);
}

__global__ __launch_bounds__(256) void scan_kernel(int* cursor, int* rowptr, int n) {
  __shared__ int part[256];
  int t = threadIdx.x;
  int per = (n + 255) / 256;
  int lo = t * per;
  int hi = lo + per; if (hi > n) hi = n;
  if (lo > n) lo = n;
  int s = 0;
  for (int i = lo; i < hi; ++i) s += cursor[i];
  part[t] = s;
  __syncthreads();
  for (int off = 1; off < 256; off <<= 1) {
    int v = (t >= off) ? part[t - off] : 0;
    __syncthreads();
    part[t] += v;
    __syncthreads();
  }
  int run = (t > 0) ? part[t - 1] : 0;
  for (int i = lo; i < hi; ++i) {
    int c = cursor[i];
    cursor[i] = run;
    rowptr[i + 1] = run + c;
    run += c;
  }
  if (t == 0) rowptr[0] = 0;
}

__global__ void fill_kernel(const int* dst, int* cursor, int* eid, int n) {
  for (int e = blockIdx.x * blockDim.x + threadIdx.x; e < n; e += gridDim.x * blockDim.x) {
    int p = atomicAdd(&cursor[dst[e]], 1);
    eid[p] = e;
  }
}

// ---------------- node projections (scalar) ----------------
__global__ __launch_bounds__(256)
void node_proj_s(const u16* HNF, const u16* nf, const u16* WnpT, const u16* W_attn,
                 float* Xs, float* Xd, float* as_, float* ad_, int full) {
  __shared__ u16 row[160];
  __shared__ float pa[160], pb[160];
  int r = blockIdx.x, t = threadIdx.x;
  if (t < 128) row[t] = full ? HNF[(size_t)r * 128 + t] : (u16)0;
  else if (t < 160) row[t] = nf[(size_t)r * 32 + (t - 128)];
  __syncthreads();
  if (t < 160) {
    float rv = b2f(row[t]);
    pa[t] = rv * b2f(W_attn[t]);
    pb[t] = rv * b2f(W_attn[160 + t]);
  }
  int c = t & 127, sel = t >> 7;
  const u16* w = WnpT + (size_t)(sel * 128 + c) * 160;
  float s = 0.f;
  for (int k = 0; k < 160; ++k) s += b2f(row[k]) * b2f(w[k]);
  (sel ? Xd : Xs)[(size_t)r * 128 + c] = s;
  __syncthreads();
  if (t == 0) { float a = 0.f; for (int k = 0; k < 160; ++k) a += pa[k]; as_[r] = a; }
  if (t == 1) { float a = 0.f; for (int k = 0; k < 160; ++k) a += pb[k]; ad_[r] = a; }
}

// ---------------- edge update (scalar, in-place m over HEF) ----------------
__global__ __launch_bounds__(128)
void edge_s(u16* HEF, const u16* ef, const u16* WeT, const u16* W_attn,
            const u16* b_edge, const u16* b_attn, const int* src, const int* dst,
            const float* Xs, const float* Xd, const float* as_, const float* ad_,
            float* logit, int full) {
  __shared__ u16 row[160];
  __shared__ float pa[128];
  long e = blockIdx.x;
  int t = threadIdx.x;
  row[t] = full ? HEF[e * 128 + t] : (u16)0;
  if (t < 32) row[128 + t] = ef[e * 32 + t];
  __syncthreads();
  float p = b2f(row[t]) * b2f(W_attn[320 + t]);
  if (t < 32) p += b2f(row[128 + t]) * b2f(W_attn[448 + t]);
  pa[t] = p;
  const u16* w = WeT + (size_t)t * 160;
  float s = 0.f;
  for (int k = 0; k < 160; ++k) s += b2f(row[k]) * b2f(w[k]);
  __syncthreads();
  for (int off = 64; off > 0; off >>= 1) {
    if (t < off) pa[t] += pa[t + off];
    __syncthreads();
  }
  int sn = src[e], dn = dst[e];
  if (t == 0) logit[e] = pa[0] + as_[sn] + ad_[dn] + b2f(b_attn[0]);
  float v = s + Xs[(size_t)sn * 128 + t] + Xd[(size_t)dn * 128 + t] + b2f(b_edge[t]);
  HEF[e * 128 + t] = f2b(fmaxf(v, 0.f));
}

// ---------------- per-dst softmax + aggregation (wave per node) ----------------
__global__ __launch_bounds__(256)
void aggregate(const int* rowptr, const int* eid, const float* logit,
               const u16* M, u16* AGG, int nrows) {
  int gw = (blockIdx.x * blockDim.x + threadIdx.x) >> 6;
  int lane = threadIdx.x & 63;
  if (gw >= nrows) return;
  int beg = rowptr[gw], end = rowptr[gw + 1];
  float acc0 = 0.f, acc1 = 0.f;
  if (beg < end) {
    float mx = logit[eid[beg]];
    for (int j = beg + 1; j < end; ++j) { float l = logit[eid[j]]; mx = fmaxf(mx, l); }
    float denom = 0.f;
    for (int j = beg; j < end; ++j) {
      int e = eid[j];
      float w = __expf(logit[e] - mx);
      denom += w;
      unsigned int mm = *(const unsigned int*)(M + (size_t)e * 128 + 2 * lane);
      acc0 += w * b2f((u16)(mm & 0xffffu));
      acc1 += w * b2f((u16)(mm >> 16));
    }
    float inv = 1.0f / fmaxf(denom, 1e-16f);
    acc0 *= inv; acc1 *= inv;
  }
  unsigned int out = (unsigned int)f2b(acc0) | ((unsigned int)f2b(acc1) << 16);
  *(unsigned int*)(AGG + (size_t)gw * 128 + 2 * lane) = out;
}

// ---------------- node update (scalar, in-place HNF) ----------------
__global__ __launch_bounds__(128)
void node_up_s(u16* HNF, const u16* nf, const u16* AGG, const u16* WnuT,
               const u16* b_node, int full) {
  __shared__ u16 row[288];
  int r = blockIdx.x, t = threadIdx.x;
  row[t] = full ? HNF[(size_t)r * 128 + t] : (u16)0;
  if (t < 32) row[128 + t] = nf[(size_t)r * 32 + t];
  row[160 + t] = AGG[(size_t)r * 128 + t];
  __syncthreads();
  const u16* w = WnuT + (size_t)t * 288;
  float s = b2f(b_node[t]);
  for (int k = 0; k < 288; ++k) s += b2f(row[k]) * b2f(w[k]);
  HNF[(size_t)r * 128 + t] = f2b(fmaxf(s, 0.f));
}

// ---------------- output heads (scalar, FP32 OUTPUT) ----------------
__global__ __launch_bounds__(256)
void head_s(const u16* IN, const u16* WT, const u16* bias, float* OUT, long R) {
  __shared__ u16 rows[8][128];
  long r0 = (long)blockIdx.x * 8;
  int t = threadIdx.x;
  for (int i = t; i < 1024; i += 256) {
    long r = r0 + (i >> 7);
    rows[i >> 7][i & 127] = (r < R) ? IN[r * 128 + (i & 127)] : (u16)0;
  }
  __syncthreads();
  int rr = t >> 5, c = t & 31;
  long r = r0 + rr;
  if (r < R) {
    const u16* w = WT + (size_t)c * 128;
    float s = b2f(bias[c]);
    for (int k = 0; k < 128; ++k) s += b2f(rows[rr][k]) * b2f(w[k]);
    OUT[r * 32 + c] = s;
  }
}

extern "C" void kernel_launch(void* const* d_in, const int* in_sizes, int n_in,
                              void* d_out, int out_size, void* d_ws, size_t ws_size,
                              hipStream_t stream) {
  const size_t REQUIRED = 166000000;
  if (ws_size < REQUIRED) return;

  const void* nf_r = d_in[0];
  const void* ef_r = d_in[1];
  const int* src = (const int*)d_in[2];
  const int* dst = (const int*)d_in[3];

  char* ws = (char*)d_ws;
  auto alloc = [&](size_t bytes) {
    char* p = ws;
    ws += (bytes + 255) & ~(size_t)255;
    return p;
  };
  u16* HEF = (u16*)alloc((size_t)GE * 128 * 2);
  u16* HNF = (u16*)alloc((size_t)GN * 128 * 2);
  float* Xs = (float*)alloc((size_t)GN * 128 * 4);
  float* Xd = (float*)alloc((size_t)GN * 128 * 4);
  float* as_ = (float*)alloc((size_t)GN * 4);
  float* ad_ = (float*)alloc((size_t)GN * 4);
  float* logit = (float*)alloc((size_t)GE * 4);
  int* rowptr = (int*)alloc((size_t)(GN + 1) * 4);
  int* cursor = (int*)alloc((size_t)GN * 4);
  int* eid = (int*)alloc((size_t)GE * 4);
  u16* WeT = (u16*)alloc(128 * 160 * 2);
  u16* WnpT = (u16*)alloc(256 * 160 * 2);
  u16* WnuT = (u16*)alloc(128 * 288 * 2);
  u16* WoN = (u16*)alloc(32 * 128 * 2);
  u16* WoE = (u16*)alloc(32 * 128 * 2);
  u16* nfc = (u16*)alloc((size_t)GN * 32 * 2);
  u16* efc = (u16*)alloc((size_t)GE * 32 * 2);
  u16* Wec = (u16*)alloc(480 * 128 * 2);
  u16* bec = (u16*)alloc(128 * 2);
  u16* Wac = (u16*)alloc(480 * 2);
  u16* bac = (u16*)alloc(2);
  u16* Wnc = (u16*)alloc(288 * 128 * 2);
  u16* bnc = (u16*)alloc(128 * 2);
  u16* Wnoc = (u16*)alloc(128 * 32 * 2);
  u16* bnoc = (u16*)alloc(32 * 2);
  u16* Weoc = (u16*)alloc(128 * 32 * 2);
  u16* beoc = (u16*)alloc(32 * 2);
  int* dflag = (int*)alloc(4);
  u16* AGG = (u16*)Xs;  // overlay: Xs dead after edge_s; consumed before rewrite

  detect_dtype<<<1, 64, 0, stream>>>(nf_r, dflag);
  convert_kernel<<<784, 256, 0, stream>>>(nf_r, nfc, (long)GN * 32, dflag);
  convert_kernel<<<6250, 256, 0, stream>>>(ef_r, efc, (long)GE * 32, dflag);
  convert_kernel<<<240, 256, 0, stream>>>(d_in[4], Wec, 480 * 128, dflag);
  convert_kernel<<<1, 128, 0, stream>>>(d_in[5], bec, 128, dflag);
  convert_kernel<<<2, 256, 0, stream>>>(d_in[6], Wac, 480, dflag);
  convert_kernel<<<1, 64, 0, stream>>>(d_in[7], bac, 1, dflag);
  convert_kernel<<<144, 256, 0, stream>>>(d_in[8], Wnc, 288 * 128, dflag);
  convert_kernel<<<1, 128, 0, stream>>>(d_in[9], bnc, 128, dflag);
  convert_kernel<<<16, 256, 0, stream>>>(d_in[10], Wnoc, 128 * 32, dflag);
  convert_kernel<<<1, 64, 0, stream>>>(d_in[11], bnoc, 32, dflag);
  convert_kernel<<<16, 256, 0, stream>>>(d_in[12], Weoc, 128 * 32, dflag);
  convert_kernel<<<1, 64, 0, stream>>>(d_in[13], beoc, 32, dflag);

  hipMemsetAsync(cursor, 0, (size_t)GN * 4, stream);
  hist_kernel<<<1563, 256, 0, stream>>>(dst, cursor, GE);
  scan_kernel<<<1, 256, 0, stream>>>(cursor, rowptr, GN);
  fill_kernel<<<1563, 256, 0, stream>>>(dst, cursor, eid, GE);
  prep_weights<<<128, 256, 0, stream>>>(Wec, Wnc, Wnoc, Weoc, WeT, WnpT, WnuT, WoN, WoE);

  for (int iter = 0; iter < 3; ++iter) {
    int full = (iter > 0) ? 1 : 0;
    node_proj_s<<<GN, 256, 0, stream>>>(HNF, nfc, WnpT, Wac, Xs, Xd, as_, ad_, full);
    edge_s<<<GE, 128, 0, stream>>>(HEF, efc, WeT, Wac, bec, bac, src, dst,
                                   Xs, Xd, as_, ad_, logit, full);
    aggregate<<<(GN + 3) / 4, 256, 0, stream>>>(rowptr, eid, logit, HEF, AGG, GN);
    node_up_s<<<GN, 128, 0, stream>>>(HNF, nfc, AGG, WnuT, bnc, full);
  }

  float* out_nf = (float*)d_out;
  float* out_ef = (float*)d_out + (size_t)GN * 32;
  head_s<<<3125, 256, 0, stream>>>(HNF, WoN, bnoc, out_nf, GN);
  head_s<<<50000, 256, 0, stream>>>(HEF, WoE, beoc, out_ef, GE);
}

// Round 6
// 3032.729 us; speedup vs baseline: 3.3403x; 3.3403x over previous
//
#include <hip/hip_runtime.h>

// IJGNN attention-MPNN, 3 iterations. fp32 in/out, bf16 internal.
// This round: edge stage -> MFMA (edge_fused); all other stages scalar (verified).

#define GN 25000
#define GE 400000
#define EDGE_BLKS 3125  // GE/128 exact

typedef unsigned short u16;
typedef __attribute__((ext_vector_type(8))) short bf16x8;
typedef __attribute__((ext_vector_type(4))) float f32x4;

__device__ inline float b2f(u16 v) {
  union { unsigned int u; float f; } x; x.u = ((unsigned int)v) << 16; return x.f;
}
__device__ inline u16 f2b(float f) {
  union { float f; unsigned int u; } x; x.f = f;
  unsigned int u = x.u;
  u += 0x7fffu + ((u >> 16) & 1u);
  return (u16)(u >> 16);
}

// ---------------- dtype probe + convert ----------------
__global__ void detect_dtype(const void* nf, int* flag) {
  if (blockIdx.x == 0 && threadIdx.x == 0) {
    const u16* p = (const u16*)nf;
    int cnt = 0;
    for (int i = 0; i < 512; i += 2) {
      int e = (p[i] >> 7) & 0xFF;
      if (e >= 0x70 && e <= 0x85) cnt++;
    }
    *flag = (cnt < 128) ? 1 : 0;
  }
}

__global__ void convert_kernel(const void* src, u16* dst, long n, const int* flag) {
  int f32 = *flag;
  long i = (long)blockIdx.x * blockDim.x + threadIdx.x;
  long stride = (long)gridDim.x * blockDim.x;
  for (; i < n; i += stride)
    dst[i] = f32 ? f2b(((const float*)src)[i]) : ((const u16*)src)[i];
}

// ---------------- weight pre-transpose ----------------
__global__ void prep_weights(const u16* We, const u16* Wn, const u16* Won, const u16* Woe,
                             u16* WeT, u16* WnpT, u16* WnuT, u16* WoN, u16* WoE) {
  int tid = blockIdx.x * blockDim.x + threadIdx.x;
  int nt = gridDim.x * blockDim.x;
  for (int i = tid; i < 128 * 160; i += nt) { int n = i / 160, k = i % 160; WeT[i] = We[(320 + k) * 128 + n]; }
  for (int i = tid; i < 256 * 160; i += nt) {
    int c = i / 160, k = i % 160;
    WnpT[i] = (c < 128) ? We[k * 128 + c] : We[(160 + k) * 128 + (c - 128)];
  }
  for (int i = tid; i < 128 * 288; i += nt) { int c = i / 288, k = i % 288; WnuT[i] = Wn[k * 128 + c]; }
  for (int i = tid; i < 32 * 128; i += nt) {
    int c = i / 128, k = i % 128;
    WoN[i] = Won[k * 32 + c];
    WoE[i] = Woe[k * 32 + c];
  }
}

// ---------------- CSR build ----------------
__global__ void hist_kernel(const int* dst, int* counts, int n) {
  for (int e = blockIdx.x * blockDim.x + threadIdx.x; e < n; e += gridDim.x * blockDim.x)
    atomicAdd(&counts[dst[e]], 1);
}

__global__ __launch_bounds__(256) void scan_kernel(int* cursor, int* rowptr, int n) {
  __shared__ int part[256];
  int t = threadIdx.x;
  int per = (n + 255) / 256;
  int lo = t * per;
  int hi = lo + per; if (hi > n) hi = n;
  if (lo > n) lo = n;
  int s = 0;
  for (int i = lo; i < hi; ++i) s += cursor[i];
  part[t] = s;
  __syncthreads();
  for (int off = 1; off < 256; off <<= 1) {
    int v = (t >= off) ? part[t - off] : 0;
    __syncthreads();
    part[t] += v;
    __syncthreads();
  }
  int run = (t > 0) ? part[t - 1] : 0;
  for (int i = lo; i < hi; ++i) {
    int c = cursor[i];
    cursor[i] = run;
    rowptr[i + 1] = run + c;
    run += c;
  }
  if (t == 0) rowptr[0] = 0;
}

__global__ void fill_kernel(const int* dst, int* cursor, int* eid, int n) {
  for (int e = blockIdx.x * blockDim.x + threadIdx.x; e < n; e += gridDim.x * blockDim.x) {
    int p = atomicAdd(&cursor[dst[e]], 1);
    eid[p] = e;
  }
}

// ---------------- node projections (scalar, verified) ----------------
__global__ __launch_bounds__(256)
void node_proj_s(const u16* HNF, const u16* nf, const u16* WnpT, const u16* W_attn,
                 float* Xs, float* Xd, float* as_, float* ad_, int full) {
  __shared__ u16 row[160];
  __shared__ float pa[160], pb[160];
  int r = blockIdx.x, t = threadIdx.x;
  if (t < 128) row[t] = full ? HNF[(size_t)r * 128 + t] : (u16)0;
  else if (t < 160) row[t] = nf[(size_t)r * 32 + (t - 128)];
  __syncthreads();
  if (t < 160) {
    float rv = b2f(row[t]);
    pa[t] = rv * b2f(W_attn[t]);
    pb[t] = rv * b2f(W_attn[160 + t]);
  }
  int c = t & 127, sel = t >> 7;
  const u16* w = WnpT + (size_t)(sel * 128 + c) * 160;
  float s = 0.f;
  for (int k = 0; k < 160; ++k) s += b2f(row[k]) * b2f(w[k]);
  (sel ? Xd : Xs)[(size_t)r * 128 + c] = s;
  __syncthreads();
  if (t == 0) { float a = 0.f; for (int k = 0; k < 160; ++k) a += pa[k]; as_[r] = a; }
  if (t == 1) { float a = 0.f; for (int k = 0; k < 160; ++k) a += pb[k]; ad_[r] = a; }
}

// ---------------- edge stage: MFMA GEMM + fused epilogue (in-place over HEF) ----------------
// C[e,col] = relu( sum_k hef_cat[e,k]*We''[k,col] + Xs[src[e],col] + Xd[dst[e],col] + b_edge[col] )
// logit[e] = hef_cat[e,:] . W_attn[320:480] + as[src] + ad[dst] + b_attn
__global__ __launch_bounds__(256)
void edge_fused(u16* HEF, const u16* ef, const u16* WeT, const u16* W_attn,
                const u16* b_edge, const u16* b_attn, const int* src, const int* dst,
                const float* Xs, const float* Xd, const float* as_, const float* ad_,
                float* logit, int kc0) {
  __shared__ __align__(16) u16 Asm[128][40];
  __shared__ __align__(16) u16 Bsm[128][40];
  __shared__ float dotbuf[128][2];
  int blk = blockIdx.x, tid = threadIdx.x;
  int lane = tid & 63, wv = tid >> 6, wr = wv & 1, wc = wv >> 1;
  f32x4 acc[4][4];
  f32x4 zf = {0.f, 0.f, 0.f, 0.f};
  for (int i = 0; i < 4; ++i) for (int j = 0; j < 4; ++j) acc[i][j] = zf;
  float dp = 0.f;
  int arow = tid >> 1, ahalf = (tid & 1) * 16;
  long e0 = (long)blk * 128;
  const u16* wa = W_attn + 320;
  for (int kc = kc0; kc < 5; ++kc) {
    {
      long e = e0 + arow;
      const uint4* p = (kc < 4) ? (const uint4*)(HEF + e * 128 + kc * 32 + ahalf)
                                : (const uint4*)(ef + e * 32 + ahalf);
      uint4 v0 = p[0], v1 = p[1];
      *(uint4*)&Asm[arow][ahalf] = v0;
      *(uint4*)&Asm[arow][ahalf + 8] = v1;
    }
    {
      const uint4* p = (const uint4*)(WeT + arow * 160 + kc * 32 + ahalf);
      uint4 v0 = p[0], v1 = p[1];
      *(uint4*)&Bsm[arow][ahalf] = v0;
      *(uint4*)&Bsm[arow][ahalf + 8] = v1;
    }
    __syncthreads();
    {
      float s = 0.f;
      for (int j = 0; j < 16; ++j) s += b2f(Asm[arow][ahalf + j]) * b2f(wa[kc * 32 + ahalf + j]);
      dp += s;
    }
    int q = lane >> 4, l16 = lane & 15;
    bf16x8 af[4], bfr[4];
    for (int i = 0; i < 4; ++i) af[i] = *(const bf16x8*)&Asm[wr * 64 + i * 16 + l16][q * 8];
    for (int j = 0; j < 4; ++j) bfr[j] = *(const bf16x8*)&Bsm[wc * 64 + j * 16 + l16][q * 8];
    for (int i = 0; i < 4; ++i)
      for (int j = 0; j < 4; ++j)
        acc[i][j] = __builtin_amdgcn_mfma_f32_16x16x32_bf16(af[i], bfr[j], acc[i][j], 0, 0, 0);
    __syncthreads();
  }
  dotbuf[arow][tid & 1] = dp;
  __syncthreads();
  if (tid < 128) {
    long e = e0 + tid;
    logit[e] = dotbuf[tid][0] + dotbuf[tid][1] + as_[src[e]] + ad_[dst[e]] + b2f(b_attn[0]);
  }
  int q = lane >> 4, l16 = lane & 15;
  for (int i = 0; i < 4; ++i)
    for (int rr = 0; rr < 4; ++rr) {
      int row = wr * 64 + i * 16 + q * 4 + rr;
      long e = e0 + row;
      int s = src[e], d = dst[e];
      for (int j = 0; j < 4; ++j) {
        int col = wc * 64 + j * 16 + l16;
        float v = acc[i][j][rr] + Xs[(size_t)s * 128 + col] + Xd[(size_t)d * 128 + col] + b2f(b_edge[col]);
        HEF[e * 128 + col] = f2b(fmaxf(v, 0.f));
      }
    }
}

// ---------------- per-dst softmax + aggregation (wave per node, verified) ----------------
__global__ __launch_bounds__(256)
void aggregate(const int* rowptr, const int* eid, const float* logit,
               const u16* M, u16* AGG, int nrows) {
  int gw = (blockIdx.x * blockDim.x + threadIdx.x) >> 6;
  int lane = threadIdx.x & 63;
  if (gw >= nrows) return;
  int beg = rowptr[gw], end = rowptr[gw + 1];
  float acc0 = 0.f, acc1 = 0.f;
  if (beg < end) {
    float mx = logit[eid[beg]];
    for (int j = beg + 1; j < end; ++j) { float l = logit[eid[j]]; mx = fmaxf(mx, l); }
    float denom = 0.f;
    for (int j = beg; j < end; ++j) {
      int e = eid[j];
      float w = __expf(logit[e] - mx);
      denom += w;
      unsigned int mm = *(const unsigned int*)(M + (size_t)e * 128 + 2 * lane);
      acc0 += w * b2f((u16)(mm & 0xffffu));
      acc1 += w * b2f((u16)(mm >> 16));
    }
    float inv = 1.0f / fmaxf(denom, 1e-16f);
    acc0 *= inv; acc1 *= inv;
  }
  unsigned int out = (unsigned int)f2b(acc0) | ((unsigned int)f2b(acc1) << 16);
  *(unsigned int*)(AGG + (size_t)gw * 128 + 2 * lane) = out;
}

// ---------------- node update (scalar, verified) ----------------
__global__ __launch_bounds__(128)
void node_up_s(u16* HNF, const u16* nf, const u16* AGG, const u16* WnuT,
               const u16* b_node, int full) {
  __shared__ u16 row[288];
  int r = blockIdx.x, t = threadIdx.x;
  row[t] = full ? HNF[(size_t)r * 128 + t] : (u16)0;
  if (t < 32) row[128 + t] = nf[(size_t)r * 32 + t];
  row[160 + t] = AGG[(size_t)r * 128 + t];
  __syncthreads();
  const u16* w = WnuT + (size_t)t * 288;
  float s = b2f(b_node[t]);
  for (int k = 0; k < 288; ++k) s += b2f(row[k]) * b2f(w[k]);
  HNF[(size_t)r * 128 + t] = f2b(fmaxf(s, 0.f));
}

// ---------------- output heads (scalar, fp32 output, verified) ----------------
__global__ __launch_bounds__(256)
void head_s(const u16* IN, const u16* WT, const u16* bias, float* OUT, long R) {
  __shared__ u16 rows[8][128];
  long r0 = (long)blockIdx.x * 8;
  int t = threadIdx.x;
  for (int i = t; i < 1024; i += 256) {
    long r = r0 + (i >> 7);
    rows[i >> 7][i & 127] = (r < R) ? IN[r * 128 + (i & 127)] : (u16)0;
  }
  __syncthreads();
  int rr = t >> 5, c = t & 31;
  long r = r0 + rr;
  if (r < R) {
    const u16* w = WT + (size_t)c * 128;
    float s = b2f(bias[c]);
    for (int k = 0; k < 128; ++k) s += b2f(rows[rr][k]) * b2f(w[k]);
    OUT[r * 32 + c] = s;
  }
}

extern "C" void kernel_launch(void* const* d_in, const int* in_sizes, int n_in,
                              void* d_out, int out_size, void* d_ws, size_t ws_size,
                              hipStream_t stream) {
  const size_t REQUIRED = 166000000;
  if (ws_size < REQUIRED) return;

  const void* nf_r = d_in[0];
  const void* ef_r = d_in[1];
  const int* src = (const int*)d_in[2];
  const int* dst = (const int*)d_in[3];

  char* ws = (char*)d_ws;
  auto alloc = [&](size_t bytes) {
    char* p = ws;
    ws += (bytes + 255) & ~(size_t)255;
    return p;
  };
  u16* HEF = (u16*)alloc((size_t)GE * 128 * 2);
  u16* HNF = (u16*)alloc((size_t)GN * 128 * 2);
  float* Xs = (float*)alloc((size_t)GN * 128 * 4);
  float* Xd = (float*)alloc((size_t)GN * 128 * 4);
  float* as_ = (float*)alloc((size_t)GN * 4);
  float* ad_ = (float*)alloc((size_t)GN * 4);
  float* logit = (float*)alloc((size_t)GE * 4);
  int* rowptr = (int*)alloc((size_t)(GN + 1) * 4);
  int* cursor = (int*)alloc((size_t)GN * 4);
  int* eid = (int*)alloc((size_t)GE * 4);
  u16* WeT = (u16*)alloc(128 * 160 * 2);
  u16* WnpT = (u16*)alloc(256 * 160 * 2);
  u16* WnuT = (u16*)alloc(128 * 288 * 2);
  u16* WoN = (u16*)alloc(32 * 128 * 2);
  u16* WoE = (u16*)alloc(32 * 128 * 2);
  u16* nfc = (u16*)alloc((size_t)GN * 32 * 2);
  u16* efc = (u16*)alloc((size_t)GE * 32 * 2);
  u16* Wec = (u16*)alloc(480 * 128 * 2);
  u16* bec = (u16*)alloc(128 * 2);
  u16* Wac = (u16*)alloc(480 * 2);
  u16* bac = (u16*)alloc(2);
  u16* Wnc = (u16*)alloc(288 * 128 * 2);
  u16* bnc = (u16*)alloc(128 * 2);
  u16* Wnoc = (u16*)alloc(128 * 32 * 2);
  u16* bnoc = (u16*)alloc(32 * 2);
  u16* Weoc = (u16*)alloc(128 * 32 * 2);
  u16* beoc = (u16*)alloc(32 * 2);
  int* dflag = (int*)alloc(4);
  u16* AGG = (u16*)Xs;  // overlay: Xs dead after edge stage; consumed before rewrite

  detect_dtype<<<1, 64, 0, stream>>>(nf_r, dflag);
  convert_kernel<<<784, 256, 0, stream>>>(nf_r, nfc, (long)GN * 32, dflag);
  convert_kernel<<<6250, 256, 0, stream>>>(ef_r, efc, (long)GE * 32, dflag);
  convert_kernel<<<240, 256, 0, stream>>>(d_in[4], Wec, 480 * 128, dflag);
  convert_kernel<<<1, 128, 0, stream>>>(d_in[5], bec, 128, dflag);
  convert_kernel<<<2, 256, 0, stream>>>(d_in[6], Wac, 480, dflag);
  convert_kernel<<<1, 64, 0, stream>>>(d_in[7], bac, 1, dflag);
  convert_kernel<<<144, 256, 0, stream>>>(d_in[8], Wnc, 288 * 128, dflag);
  convert_kernel<<<1, 128, 0, stream>>>(d_in[9], bnc, 128, dflag);
  convert_kernel<<<16, 256, 0, stream>>>(d_in[10], Wnoc, 128 * 32, dflag);
  convert_kernel<<<1, 64, 0, stream>>>(d_in[11], bnoc, 32, dflag);
  convert_kernel<<<16, 256, 0, stream>>>(d_in[12], Weoc, 128 * 32, dflag);
  convert_kernel<<<1, 64, 0, stream>>>(d_in[13], beoc, 32, dflag);

  hipMemsetAsync(cursor, 0, (size_t)GN * 4, stream);
  hist_kernel<<<1563, 256, 0, stream>>>(dst, cursor, GE);
  scan_kernel<<<1, 256, 0, stream>>>(cursor, rowptr, GN);
  fill_kernel<<<1563, 256, 0, stream>>>(dst, cursor, eid, GE);
  prep_weights<<<128, 256, 0, stream>>>(Wec, Wnc, Wnoc, Weoc, WeT, WnpT, WnuT, WoN, WoE);

  for (int iter = 0; iter < 3; ++iter) {
    int full = (iter > 0) ? 1 : 0;
    int kc0 = full ? 0 : 4;
    node_proj_s<<<GN, 256, 0, stream>>>(HNF, nfc, WnpT, Wac, Xs, Xd, as_, ad_, full);
    edge_fused<<<EDGE_BLKS, 256, 0, stream>>>(HEF, efc, WeT, Wac, bec, bac, src, dst,
                                              Xs, Xd, as_, ad_, logit, kc0);
    aggregate<<<(GN + 3) / 4, 256, 0, stream>>>(rowptr, eid, logit, HEF, AGG, GN);
    node_up_s<<<GN, 128, 0, stream>>>(HNF, nfc, AGG, WnuT, bnc, full);
  }

  float* out_nf = (float*)d_out;
  float* out_ef = (float*)d_out + (size_t)GN * 32;
  head_s<<<3125, 256, 0, stream>>>(HNF, WoN, bnoc, out_nf, GN);
  head_s<<<50000, 256, 0, stream>>>(HEF, WoE, beoc, out_ef, GE);
}

// Round 7
// 976.506 us; speedup vs baseline: 10.3738x; 3.1057x over previous
//
#include <hip/hip_runtime.h>

// IJGNN attention-MPNN, 3 iterations. fp32 in/out, bf16 internal.
// All four GEMM stages on MFMA (fragment layout HW-verified via round-6 edge_fused).

#define GN 25000
#define GE 400000
#define NODE_BLKS 196   // ceil(GN/128)
#define EDGE_BLKS 3125  // GE/128 exact

typedef unsigned short u16;
typedef __attribute__((ext_vector_type(8))) short bf16x8;
typedef __attribute__((ext_vector_type(4))) float f32x4;

__device__ inline float b2f(u16 v) {
  union { unsigned int u; float f; } x; x.u = ((unsigned int)v) << 16; return x.f;
}
__device__ inline u16 f2b(float f) {
  union { float f; unsigned int u; } x; x.f = f;
  unsigned int u = x.u;
  u += 0x7fffu + ((u >> 16) & 1u);
  return (u16)(u >> 16);
}

// ---------------- dtype probe + convert ----------------
__global__ void detect_dtype(const void* nf, int* flag) {
  if (blockIdx.x == 0 && threadIdx.x == 0) {
    const u16* p = (const u16*)nf;
    int cnt = 0;
    for (int i = 0; i < 512; i += 2) {
      int e = (p[i] >> 7) & 0xFF;
      if (e >= 0x70 && e <= 0x85) cnt++;
    }
    *flag = (cnt < 128) ? 1 : 0;
  }
}

__global__ void convert_kernel(const void* src, u16* dst, long n, const int* flag) {
  int f32 = *flag;
  long i = (long)blockIdx.x * blockDim.x + threadIdx.x;
  long stride = (long)gridDim.x * blockDim.x;
  for (; i < n; i += stride)
    dst[i] = f32 ? f2b(((const float*)src)[i]) : ((const u16*)src)[i];
}

// ---------------- weight pre-transpose ----------------
__global__ void prep_weights(const u16* We, const u16* Wn, const u16* Won, const u16* Woe,
                             u16* WeT, u16* WnpT, u16* WnuT, u16* WoN, u16* WoE) {
  int tid = blockIdx.x * blockDim.x + threadIdx.x;
  int nt = gridDim.x * blockDim.x;
  for (int i = tid; i < 128 * 160; i += nt) { int n = i / 160, k = i % 160; WeT[i] = We[(320 + k) * 128 + n]; }
  for (int i = tid; i < 256 * 160; i += nt) {
    int c = i / 160, k = i % 160;
    WnpT[i] = (c < 128) ? We[k * 128 + c] : We[(160 + k) * 128 + (c - 128)];
  }
  for (int i = tid; i < 128 * 288; i += nt) { int c = i / 288, k = i % 288; WnuT[i] = Wn[k * 128 + c]; }
  for (int i = tid; i < 32 * 128; i += nt) {
    int c = i / 128, k = i % 128;
    WoN[i] = Won[k * 32 + c];
    WoE[i] = Woe[k * 32 + c];
  }
}

// ---------------- CSR build ----------------
__global__ void hist_kernel(const int* dst, int* counts, int n) {
  for (int e = blockIdx.x * blockDim.x + threadIdx.x; e < n; e += gridDim.x * blockDim.x)
    atomicAdd(&counts[dst[e]], 1);
}

__global__ __launch_bounds__(256) void scan_kernel(int* cursor, int* rowptr, int n) {
  __shared__ int part[256];
  int t = threadIdx.x;
  int per = (n + 255) / 256;
  int lo = t * per;
  int hi = lo + per; if (hi > n) hi = n;
  if (lo > n) lo = n;
  int s = 0;
  for (int i = lo; i < hi; ++i) s += cursor[i];
  part[t] = s;
  __syncthreads();
  for (int off = 1; off < 256; off <<= 1) {
    int v = (t >= off) ? part[t - off] : 0;
    __syncthreads();
    part[t] += v;
    __syncthreads();
  }
  int run = (t > 0) ? part[t - 1] : 0;
  for (int i = lo; i < hi; ++i) {
    int c = cursor[i];
    cursor[i] = run;
    rowptr[i + 1] = run + c;
    run += c;
  }
  if (t == 0) rowptr[0] = 0;
}

__global__ void fill_kernel(const int* dst, int* cursor, int* eid, int n) {
  for (int e = blockIdx.x * blockDim.x + threadIdx.x; e < n; e += gridDim.x * blockDim.x) {
    int p = atomicAdd(&cursor[dst[e]], 1);
    eid[p] = e;
  }
}

// ---------------- node projections (MFMA): Xs/Xd [N,128] fp32, as/ad [N] ----------------
__global__ __launch_bounds__(256)
void node_proj(const u16* HNF, const u16* nf, const u16* WnpT, const u16* W_attn,
               float* Xs, float* Xd, float* as_, float* ad_, int kc0, int nrows) {
  __shared__ __align__(16) u16 Asm[128][40];
  __shared__ __align__(16) u16 Bsm[128][40];
  __shared__ float dotbuf[128][2];
  int sel = blockIdx.y, blk = blockIdx.x, tid = threadIdx.x;
  int lane = tid & 63, wv = tid >> 6, wr = wv & 1, wc = wv >> 1;
  const u16* BT = WnpT + sel * 128 * 160;
  float* OUT = sel ? Xd : Xs;
  float* AOUT = sel ? ad_ : as_;
  const u16* wa = W_attn + sel * 160;
  f32x4 acc[4][4];
  f32x4 zf = {0.f, 0.f, 0.f, 0.f};
  for (int i = 0; i < 4; ++i) for (int j = 0; j < 4; ++j) acc[i][j] = zf;
  float dp = 0.f;
  int arow = tid >> 1, ahalf = (tid & 1) * 16;
  int r0 = blk * 128;
  for (int kc = kc0; kc < 5; ++kc) {
    {
      int r = r0 + arow;
      uint4 v0 = make_uint4(0, 0, 0, 0), v1 = make_uint4(0, 0, 0, 0);
      if (r < nrows) {
        const uint4* p = (kc < 4) ? (const uint4*)(HNF + (size_t)r * 128 + kc * 32 + ahalf)
                                  : (const uint4*)(nf + (size_t)r * 32 + ahalf);
        v0 = p[0]; v1 = p[1];
      }
      *(uint4*)&Asm[arow][ahalf] = v0;
      *(uint4*)&Asm[arow][ahalf + 8] = v1;
    }
    {
      const uint4* p = (const uint4*)(BT + arow * 160 + kc * 32 + ahalf);
      uint4 v0 = p[0], v1 = p[1];
      *(uint4*)&Bsm[arow][ahalf] = v0;
      *(uint4*)&Bsm[arow][ahalf + 8] = v1;
    }
    __syncthreads();
    {
      float s = 0.f;
      for (int j = 0; j < 16; ++j) s += b2f(Asm[arow][ahalf + j]) * b2f(wa[kc * 32 + ahalf + j]);
      dp += s;
    }
    int q = lane >> 4, l16 = lane & 15;
    bf16x8 af[4], bfr[4];
    for (int i = 0; i < 4; ++i) af[i] = *(const bf16x8*)&Asm[wr * 64 + i * 16 + l16][q * 8];
    for (int j = 0; j < 4; ++j) bfr[j] = *(const bf16x8*)&Bsm[wc * 64 + j * 16 + l16][q * 8];
    for (int i = 0; i < 4; ++i)
      for (int j = 0; j < 4; ++j)
        acc[i][j] = __builtin_amdgcn_mfma_f32_16x16x32_bf16(af[i], bfr[j], acc[i][j], 0, 0, 0);
    __syncthreads();
  }
  dotbuf[arow][tid & 1] = dp;
  __syncthreads();
  if (tid < 128) {
    int r = r0 + tid;
    if (r < nrows) AOUT[r] = dotbuf[tid][0] + dotbuf[tid][1];
  }
  int q = lane >> 4, l16 = lane & 15;
  for (int i = 0; i < 4; ++i)
    for (int rr = 0; rr < 4; ++rr) {
      int row = wr * 64 + i * 16 + q * 4 + rr;
      int r = r0 + row;
      if (r < nrows)
        for (int j = 0; j < 4; ++j) {
          int col = wc * 64 + j * 16 + l16;
          OUT[(size_t)r * 128 + col] = acc[i][j][rr];
        }
    }
}

// ---------------- edge stage: MFMA GEMM + fused epilogue (in-place over HEF) ----------------
__global__ __launch_bounds__(256)
void edge_fused(u16* HEF, const u16* ef, const u16* WeT, const u16* W_attn,
                const u16* b_edge, const u16* b_attn, const int* src, const int* dst,
                const float* Xs, const float* Xd, const float* as_, const float* ad_,
                float* logit, int kc0) {
  __shared__ __align__(16) u16 Asm[128][40];
  __shared__ __align__(16) u16 Bsm[128][40];
  __shared__ float dotbuf[128][2];
  int blk = blockIdx.x, tid = threadIdx.x;
  int lane = tid & 63, wv = tid >> 6, wr = wv & 1, wc = wv >> 1;
  f32x4 acc[4][4];
  f32x4 zf = {0.f, 0.f, 0.f, 0.f};
  for (int i = 0; i < 4; ++i) for (int j = 0; j < 4; ++j) acc[i][j] = zf;
  float dp = 0.f;
  int arow = tid >> 1, ahalf = (tid & 1) * 16;
  long e0 = (long)blk * 128;
  const u16* wa = W_attn + 320;
  for (int kc = kc0; kc < 5; ++kc) {
    {
      long e = e0 + arow;
      const uint4* p = (kc < 4) ? (const uint4*)(HEF + e * 128 + kc * 32 + ahalf)
                                : (const uint4*)(ef + e * 32 + ahalf);
      uint4 v0 = p[0], v1 = p[1];
      *(uint4*)&Asm[arow][ahalf] = v0;
      *(uint4*)&Asm[arow][ahalf + 8] = v1;
    }
    {
      const uint4* p = (const uint4*)(WeT + arow * 160 + kc * 32 + ahalf);
      uint4 v0 = p[0], v1 = p[1];
      *(uint4*)&Bsm[arow][ahalf] = v0;
      *(uint4*)&Bsm[arow][ahalf + 8] = v1;
    }
    __syncthreads();
    {
      float s = 0.f;
      for (int j = 0; j < 16; ++j) s += b2f(Asm[arow][ahalf + j]) * b2f(wa[kc * 32 + ahalf + j]);
      dp += s;
    }
    int q = lane >> 4, l16 = lane & 15;
    bf16x8 af[4], bfr[4];
    for (int i = 0; i < 4; ++i) af[i] = *(const bf16x8*)&Asm[wr * 64 + i * 16 + l16][q * 8];
    for (int j = 0; j < 4; ++j) bfr[j] = *(const bf16x8*)&Bsm[wc * 64 + j * 16 + l16][q * 8];
    for (int i = 0; i < 4; ++i)
      for (int j = 0; j < 4; ++j)
        acc[i][j] = __builtin_amdgcn_mfma_f32_16x16x32_bf16(af[i], bfr[j], acc[i][j], 0, 0, 0);
    __syncthreads();
  }
  dotbuf[arow][tid & 1] = dp;
  __syncthreads();
  if (tid < 128) {
    long e = e0 + tid;
    logit[e] = dotbuf[tid][0] + dotbuf[tid][1] + as_[src[e]] + ad_[dst[e]] + b2f(b_attn[0]);
  }
  int q = lane >> 4, l16 = lane & 15;
  for (int i = 0; i < 4; ++i)
    for (int rr = 0; rr < 4; ++rr) {
      int row = wr * 64 + i * 16 + q * 4 + rr;
      long e = e0 + row;
      int s = src[e], d = dst[e];
      for (int j = 0; j < 4; ++j) {
        int col = wc * 64 + j * 16 + l16;
        float v = acc[i][j][rr] + Xs[(size_t)s * 128 + col] + Xd[(size_t)d * 128 + col] + b2f(b_edge[col]);
        HEF[e * 128 + col] = f2b(fmaxf(v, 0.f));
      }
    }
}

// ---------------- per-dst softmax + aggregation (wave per node, verified) ----------------
__global__ __launch_bounds__(256)
void aggregate(const int* rowptr, const int* eid, const float* logit,
               const u16* M, u16* AGG, int nrows) {
  int gw = (blockIdx.x * blockDim.x + threadIdx.x) >> 6;
  int lane = threadIdx.x & 63;
  if (gw >= nrows) return;
  int beg = rowptr[gw], end = rowptr[gw + 1];
  float acc0 = 0.f, acc1 = 0.f;
  if (beg < end) {
    float mx = logit[eid[beg]];
    for (int j = beg + 1; j < end; ++j) { float l = logit[eid[j]]; mx = fmaxf(mx, l); }
    float denom = 0.f;
    for (int j = beg; j < end; ++j) {
      int e = eid[j];
      float w = __expf(logit[e] - mx);
      denom += w;
      unsigned int mm = *(const unsigned int*)(M + (size_t)e * 128 + 2 * lane);
      acc0 += w * b2f((u16)(mm & 0xffffu));
      acc1 += w * b2f((u16)(mm >> 16));
    }
    float inv = 1.0f / fmaxf(denom, 1e-16f);
    acc0 *= inv; acc1 *= inv;
  }
  unsigned int out = (unsigned int)f2b(acc0) | ((unsigned int)f2b(acc1) << 16);
  *(unsigned int*)(AGG + (size_t)gw * 128 + 2 * lane) = out;
}

// ---------------- node update (MFMA, in-place HNF) ----------------
__global__ __launch_bounds__(256)
void node_update(u16* HNF, const u16* nf, const u16* AGG, const u16* WnuT,
                 const u16* b_node, int kc0, int nrows) {
  __shared__ __align__(16) u16 Asm[128][40];
  __shared__ __align__(16) u16 Bsm[128][40];
  int blk = blockIdx.x, tid = threadIdx.x;
  int lane = tid & 63, wv = tid >> 6, wr = wv & 1, wc = wv >> 1;
  f32x4 acc[4][4];
  f32x4 zf = {0.f, 0.f, 0.f, 0.f};
  for (int i = 0; i < 4; ++i) for (int j = 0; j < 4; ++j) acc[i][j] = zf;
  int arow = tid >> 1, ahalf = (tid & 1) * 16;
  int r0 = blk * 128;
  for (int kc = kc0; kc < 9; ++kc) {
    {
      int r = r0 + arow;
      uint4 v0 = make_uint4(0, 0, 0, 0), v1 = make_uint4(0, 0, 0, 0);
      if (r < nrows) {
        const u16* p;
        if (kc < 4) p = HNF + (size_t)r * 128 + kc * 32 + ahalf;
        else if (kc == 4) p = nf + (size_t)r * 32 + ahalf;
        else p = AGG + (size_t)r * 128 + (kc - 5) * 32 + ahalf;
        v0 = ((const uint4*)p)[0];
        v1 = ((const uint4*)p)[1];
      }
      *(uint4*)&Asm[arow][ahalf] = v0;
      *(uint4*)&Asm[arow][ahalf + 8] = v1;
    }
    {
      const uint4* p = (const uint4*)(WnuT + arow * 288 + kc * 32 + ahalf);
      uint4 v0 = p[0], v1 = p[1];
      *(uint4*)&Bsm[arow][ahalf] = v0;
      *(uint4*)&Bsm[arow][ahalf + 8] = v1;
    }
    __syncthreads();
    int q = lane >> 4, l16 = lane & 15;
    bf16x8 af[4], bfr[4];
    for (int i = 0; i < 4; ++i) af[i] = *(const bf16x8*)&Asm[wr * 64 + i * 16 + l16][q * 8];
    for (int j = 0; j < 4; ++j) bfr[j] = *(const bf16x8*)&Bsm[wc * 64 + j * 16 + l16][q * 8];
    for (int i = 0; i < 4; ++i)
      for (int j = 0; j < 4; ++j)
        acc[i][j] = __builtin_amdgcn_mfma_f32_16x16x32_bf16(af[i], bfr[j], acc[i][j], 0, 0, 0);
    __syncthreads();
  }
  int q = lane >> 4, l16 = lane & 15;
  for (int i = 0; i < 4; ++i)
    for (int rr = 0; rr < 4; ++rr) {
      int row = wr * 64 + i * 16 + q * 4 + rr;
      int r = r0 + row;
      if (r < nrows)
        for (int j = 0; j < 4; ++j) {
          int col = wc * 64 + j * 16 + l16;
          float v = acc[i][j][rr] + b2f(b_node[col]);
          HNF[(size_t)r * 128 + col] = f2b(fmaxf(v, 0.f));
        }
    }
}

// ---------------- output heads (MFMA, fp32 output) ----------------
__global__ __launch_bounds__(256)
void head_kernel(const u16* IN, const u16* WT, const u16* bias, float* OUT, long R) {
  __shared__ __align__(16) u16 Asm[128][40];
  __shared__ __align__(16) u16 Bsm[32][40];
  int blk = blockIdx.x, tid = threadIdx.x;
  int lane = tid & 63, wv = tid >> 6;
  f32x4 acc[2][2];
  f32x4 zf = {0.f, 0.f, 0.f, 0.f};
  for (int i = 0; i < 2; ++i) for (int j = 0; j < 2; ++j) acc[i][j] = zf;
  int arow = tid >> 1, ahalf = (tid & 1) * 16;
  long r0 = (long)blk * 128;
  for (int kc = 0; kc < 4; ++kc) {
    {
      long r = r0 + arow;
      uint4 v0 = make_uint4(0, 0, 0, 0), v1 = make_uint4(0, 0, 0, 0);
      if (r < R) {
        const uint4* p = (const uint4*)(IN + r * 128 + kc * 32 + ahalf);
        v0 = p[0]; v1 = p[1];
      }
      *(uint4*)&Asm[arow][ahalf] = v0;
      *(uint4*)&Asm[arow][ahalf + 8] = v1;
    }
    if (tid < 64) {
      const uint4* p = (const uint4*)(WT + arow * 128 + kc * 32 + ahalf);
      uint4 v0 = p[0], v1 = p[1];
      *(uint4*)&Bsm[arow][ahalf] = v0;
      *(uint4*)&Bsm[arow][ahalf + 8] = v1;
    }
    __syncthreads();
    int q = lane >> 4, l16 = lane & 15;
    bf16x8 af[2], bfr[2];
    for (int i = 0; i < 2; ++i) af[i] = *(const bf16x8*)&Asm[wv * 32 + i * 16 + l16][q * 8];
    for (int j = 0; j < 2; ++j) bfr[j] = *(const bf16x8*)&Bsm[j * 16 + l16][q * 8];
    for (int i = 0; i < 2; ++i)
      for (int j = 0; j < 2; ++j)
        acc[i][j] = __builtin_amdgcn_mfma_f32_16x16x32_bf16(af[i], bfr[j], acc[i][j], 0, 0, 0);
    __syncthreads();
  }
  int q = lane >> 4, l16 = lane & 15;
  for (int i = 0; i < 2; ++i)
    for (int rr = 0; rr < 4; ++rr) {
      long r = r0 + wv * 32 + i * 16 + q * 4 + rr;
      if (r < R)
        for (int j = 0; j < 2; ++j) {
          int col = j * 16 + l16;
          OUT[r * 32 + col] = acc[i][j][rr] + b2f(bias[col]);
        }
    }
}

extern "C" void kernel_launch(void* const* d_in, const int* in_sizes, int n_in,
                              void* d_out, int out_size, void* d_ws, size_t ws_size,
                              hipStream_t stream) {
  const size_t REQUIRED = 166000000;
  if (ws_size < REQUIRED) return;

  const void* nf_r = d_in[0];
  const void* ef_r = d_in[1];
  const int* src = (const int*)d_in[2];
  const int* dst = (const int*)d_in[3];

  char* ws = (char*)d_ws;
  auto alloc = [&](size_t bytes) {
    char* p = ws;
    ws += (bytes + 255) & ~(size_t)255;
    return p;
  };
  u16* HEF = (u16*)alloc((size_t)GE * 128 * 2);
  u16* HNF = (u16*)alloc((size_t)GN * 128 * 2);
  float* Xs = (float*)alloc((size_t)GN * 128 * 4);
  float* Xd = (float*)alloc((size_t)GN * 128 * 4);
  float* as_ = (float*)alloc((size_t)GN * 4);
  float* ad_ = (float*)alloc((size_t)GN * 4);
  float* logit = (float*)alloc((size_t)GE * 4);
  int* rowptr = (int*)alloc((size_t)(GN + 1) * 4);
  int* cursor = (int*)alloc((size_t)GN * 4);
  int* eid = (int*)alloc((size_t)GE * 4);
  u16* WeT = (u16*)alloc(128 * 160 * 2);
  u16* WnpT = (u16*)alloc(256 * 160 * 2);
  u16* WnuT = (u16*)alloc(128 * 288 * 2);
  u16* WoN = (u16*)alloc(32 * 128 * 2);
  u16* WoE = (u16*)alloc(32 * 128 * 2);
  u16* nfc = (u16*)alloc((size_t)GN * 32 * 2);
  u16* efc = (u16*)alloc((size_t)GE * 32 * 2);
  u16* Wec = (u16*)alloc(480 * 128 * 2);
  u16* bec = (u16*)alloc(128 * 2);
  u16* Wac = (u16*)alloc(480 * 2);
  u16* bac = (u16*)alloc(2);
  u16* Wnc = (u16*)alloc(288 * 128 * 2);
  u16* bnc = (u16*)alloc(128 * 2);
  u16* Wnoc = (u16*)alloc(128 * 32 * 2);
  u16* bnoc = (u16*)alloc(32 * 2);
  u16* Weoc = (u16*)alloc(128 * 32 * 2);
  u16* beoc = (u16*)alloc(32 * 2);
  int* dflag = (int*)alloc(4);
  u16* AGG = (u16*)Xs;  // overlay: Xs dead after edge stage; consumed before rewrite

  detect_dtype<<<1, 64, 0, stream>>>(nf_r, dflag);
  convert_kernel<<<784, 256, 0, stream>>>(nf_r, nfc, (long)GN * 32, dflag);
  convert_kernel<<<6250, 256, 0, stream>>>(ef_r, efc, (long)GE * 32, dflag);
  convert_kernel<<<240, 256, 0, stream>>>(d_in[4], Wec, 480 * 128, dflag);
  convert_kernel<<<1, 128, 0, stream>>>(d_in[5], bec, 128, dflag);
  convert_kernel<<<2, 256, 0, stream>>>(d_in[6], Wac, 480, dflag);
  convert_kernel<<<1, 64, 0, stream>>>(d_in[7], bac, 1, dflag);
  convert_kernel<<<144, 256, 0, stream>>>(d_in[8], Wnc, 288 * 128, dflag);
  convert_kernel<<<1, 128, 0, stream>>>(d_in[9], bnc, 128, dflag);
  convert_kernel<<<16, 256, 0, stream>>>(d_in[10], Wnoc, 128 * 32, dflag);
  convert_kernel<<<1, 64, 0, stream>>>(d_in[11], bnoc, 32, dflag);
  convert_kernel<<<16, 256, 0, stream>>>(d_in[12], Weoc, 128 * 32, dflag);
  convert_kernel<<<1, 64, 0, stream>>>(d_in[13], beoc, 32, dflag);

  hipMemsetAsync(cursor, 0, (size_t)GN * 4, stream);
  hist_kernel<<<1563, 256, 0, stream>>>(dst, cursor, GE);
  scan_kernel<<<1, 256, 0, stream>>>(cursor, rowptr, GN);
  fill_kernel<<<1563, 256, 0, stream>>>(dst, cursor, eid, GE);
  prep_weights<<<128, 256, 0, stream>>>(Wec, Wnc, Wnoc, Weoc, WeT, WnpT, WnuT, WoN, WoE);

  for (int iter = 0; iter < 3; ++iter) {
    int kc0 = (iter == 0) ? 4 : 0;
    dim3 npgrid(NODE_BLKS, 2);
    node_proj<<<npgrid, 256, 0, stream>>>(HNF, nfc, WnpT, Wac, Xs, Xd, as_, ad_, kc0, GN);
    edge_fused<<<EDGE_BLKS, 256, 0, stream>>>(HEF, efc, WeT, Wac, bec, bac, src, dst,
                                              Xs, Xd, as_, ad_, logit, kc0);
    aggregate<<<(GN + 3) / 4, 256, 0, stream>>>(rowptr, eid, logit, HEF, AGG, GN);
    node_update<<<NODE_BLKS, 256, 0, stream>>>(HNF, nfc, AGG, WnuT, bnc, kc0, GN);
  }

  float* out_nf = (float*)d_out;
  float* out_ef = (float*)d_out + (size_t)GN * 32;
  head_kernel<<<NODE_BLKS, 256, 0, stream>>>(HNF, WoN, bnoc, out_nf, GN);
  head_kernel<<<EDGE_BLKS, 256, 0, stream>>>(HEF, WoE, beoc, out_ef, GE);
}

// Round 8
// 963.292 us; speedup vs baseline: 10.5161x; 1.0137x over previous
//
#include <hip/hip_runtime.h>

// IJGNN attention-MPNN, 3 iterations. fp32 in/out, bf16 internal.
// Edges processed in dst-sorted (CSR) order; edge head scatters back via eid.
// edge_fused: attn-dot from MFMA fragments (no scalar LDS dot); Xs/Xd bf16.

#define GN 25000
#define GE 400000
#define NODE_BLKS 196   // ceil(GN/128)
#define EDGE_BLKS 3125  // GE/128 exact

typedef unsigned short u16;
typedef __attribute__((ext_vector_type(8))) short bf16x8;
typedef __attribute__((ext_vector_type(4))) float f32x4;

__device__ inline float b2f(u16 v) {
  union { unsigned int u; float f; } x; x.u = ((unsigned int)v) << 16; return x.f;
}
__device__ inline u16 f2b(float f) {
  union { float f; unsigned int u; } x; x.f = f;
  unsigned int u = x.u;
  u += 0x7fffu + ((u >> 16) & 1u);
  return (u16)(u >> 16);
}

// ---------------- dtype probe + convert ----------------
__global__ void detect_dtype(const void* nf, int* flag) {
  if (blockIdx.x == 0 && threadIdx.x == 0) {
    const u16* p = (const u16*)nf;
    int cnt = 0;
    for (int i = 0; i < 512; i += 2) {
      int e = (p[i] >> 7) & 0xFF;
      if (e >= 0x70 && e <= 0x85) cnt++;
    }
    *flag = (cnt < 128) ? 1 : 0;
  }
}

__global__ void convert_kernel(const void* src, u16* dst, long n, const int* flag) {
  int f32 = *flag;
  long i = (long)blockIdx.x * blockDim.x + threadIdx.x;
  long stride = (long)gridDim.x * blockDim.x;
  for (; i < n; i += stride)
    dst[i] = f32 ? f2b(((const float*)src)[i]) : ((const u16*)src)[i];
}

// gather ef rows into dst-sorted order (+convert)
__global__ void gather_ef(const void* ef, const int* eid, u16* efc, const int* flag) {
  int f32 = *flag;
  long idx = (long)blockIdx.x * blockDim.x + threadIdx.x;
  long stride = (long)gridDim.x * blockDim.x;
  long ntot = (long)GE * 32;
  for (; idx < ntot; idx += stride) {
    long j = idx >> 5;
    int c = (int)(idx & 31);
    long e = eid[j];
    efc[idx] = f32 ? f2b(((const float*)ef)[e * 32 + c]) : ((const u16*)ef)[e * 32 + c];
  }
}

__global__ void gather_meta(const int* src, const int* dst, const int* eid,
                            int* srcs, int* dsts, int n) {
  int j = blockIdx.x * blockDim.x + threadIdx.x;
  if (j < n) { int e = eid[j]; srcs[j] = src[e]; dsts[j] = dst[e]; }
}

// ---------------- weight pre-transpose ----------------
__global__ void prep_weights(const u16* We, const u16* Wn, const u16* Won, const u16* Woe,
                             u16* WeT, u16* WnpT, u16* WnuT, u16* WoN, u16* WoE) {
  int tid = blockIdx.x * blockDim.x + threadIdx.x;
  int nt = gridDim.x * blockDim.x;
  for (int i = tid; i < 128 * 160; i += nt) { int n = i / 160, k = i % 160; WeT[i] = We[(320 + k) * 128 + n]; }
  for (int i = tid; i < 256 * 160; i += nt) {
    int c = i / 160, k = i % 160;
    WnpT[i] = (c < 128) ? We[k * 128 + c] : We[(160 + k) * 128 + (c - 128)];
  }
  for (int i = tid; i < 128 * 288; i += nt) { int c = i / 288, k = i % 288; WnuT[i] = Wn[k * 128 + c]; }
  for (int i = tid; i < 32 * 128; i += nt) {
    int c = i / 128, k = i % 128;
    WoN[i] = Won[k * 32 + c];
    WoE[i] = Woe[k * 32 + c];
  }
}

// ---------------- CSR build ----------------
__global__ void hist_kernel(const int* dst, int* counts, int n) {
  for (int e = blockIdx.x * blockDim.x + threadIdx.x; e < n; e += gridDim.x * blockDim.x)
    atomicAdd(&counts[dst[e]], 1);
}

__global__ __launch_bounds__(256) void scan_kernel(int* cursor, int* rowptr, int n) {
  __shared__ int part[256];
  int t = threadIdx.x;
  int per = (n + 255) / 256;
  int lo = t * per;
  int hi = lo + per; if (hi > n) hi = n;
  if (lo > n) lo = n;
  int s = 0;
  for (int i = lo; i < hi; ++i) s += cursor[i];
  part[t] = s;
  __syncthreads();
  for (int off = 1; off < 256; off <<= 1) {
    int v = (t >= off) ? part[t - off] : 0;
    __syncthreads();
    part[t] += v;
    __syncthreads();
  }
  int run = (t > 0) ? part[t - 1] : 0;
  for (int i = lo; i < hi; ++i) {
    int c = cursor[i];
    cursor[i] = run;
    rowptr[i + 1] = run + c;
    run += c;
  }
  if (t == 0) rowptr[0] = 0;
}

__global__ void fill_kernel(const int* dst, int* cursor, int* eid, int n) {
  for (int e = blockIdx.x * blockDim.x + threadIdx.x; e < n; e += gridDim.x * blockDim.x) {
    int p = atomicAdd(&cursor[dst[e]], 1);
    eid[p] = e;
  }
}

// ---------------- node projections (MFMA): Xs/Xd [N,128] bf16, as/ad [N] fp32 ----------------
__global__ __launch_bounds__(256)
void node_proj(const u16* HNF, const u16* nf, const u16* WnpT, const u16* W_attn,
               u16* Xs, u16* Xd, float* as_, float* ad_, int kc0, int nrows) {
  __shared__ __align__(16) u16 Asm[128][40];
  __shared__ __align__(16) u16 Bsm[128][40];
  __shared__ float dotbuf[128][2];
  int sel = blockIdx.y, blk = blockIdx.x, tid = threadIdx.x;
  int lane = tid & 63, wv = tid >> 6, wr = wv & 1, wc = wv >> 1;
  const u16* BT = WnpT + sel * 128 * 160;
  u16* OUT = sel ? Xd : Xs;
  float* AOUT = sel ? ad_ : as_;
  const u16* wa = W_attn + sel * 160;
  f32x4 acc[4][4];
  f32x4 zf = {0.f, 0.f, 0.f, 0.f};
  for (int i = 0; i < 4; ++i) for (int j = 0; j < 4; ++j) acc[i][j] = zf;
  float dp = 0.f;
  int arow = tid >> 1, ahalf = (tid & 1) * 16;
  int r0 = blk * 128;
  for (int kc = kc0; kc < 5; ++kc) {
    {
      int r = r0 + arow;
      uint4 v0 = make_uint4(0, 0, 0, 0), v1 = make_uint4(0, 0, 0, 0);
      if (r < nrows) {
        const uint4* p = (kc < 4) ? (const uint4*)(HNF + (size_t)r * 128 + kc * 32 + ahalf)
                                  : (const uint4*)(nf + (size_t)r * 32 + ahalf);
        v0 = p[0]; v1 = p[1];
      }
      *(uint4*)&Asm[arow][ahalf] = v0;
      *(uint4*)&Asm[arow][ahalf + 8] = v1;
    }
    {
      const uint4* p = (const uint4*)(BT + arow * 160 + kc * 32 + ahalf);
      uint4 v0 = p[0], v1 = p[1];
      *(uint4*)&Bsm[arow][ahalf] = v0;
      *(uint4*)&Bsm[arow][ahalf + 8] = v1;
    }
    __syncthreads();
    {
      float s = 0.f;
      for (int j = 0; j < 16; ++j) s += b2f(Asm[arow][ahalf + j]) * b2f(wa[kc * 32 + ahalf + j]);
      dp += s;
    }
    int q = lane >> 4, l16 = lane & 15;
    bf16x8 af[4], bfr[4];
    for (int i = 0; i < 4; ++i) af[i] = *(const bf16x8*)&Asm[wr * 64 + i * 16 + l16][q * 8];
    for (int j = 0; j < 4; ++j) bfr[j] = *(const bf16x8*)&Bsm[wc * 64 + j * 16 + l16][q * 8];
    for (int i = 0; i < 4; ++i)
      for (int j = 0; j < 4; ++j)
        acc[i][j] = __builtin_amdgcn_mfma_f32_16x16x32_bf16(af[i], bfr[j], acc[i][j], 0, 0, 0);
    __syncthreads();
  }
  dotbuf[arow][tid & 1] = dp;
  __syncthreads();
  if (tid < 128) {
    int r = r0 + tid;
    if (r < nrows) AOUT[r] = dotbuf[tid][0] + dotbuf[tid][1];
  }
  int q = lane >> 4, l16 = lane & 15;
  for (int i = 0; i < 4; ++i)
    for (int rr = 0; rr < 4; ++rr) {
      int row = wr * 64 + i * 16 + q * 4 + rr;
      int r = r0 + row;
      if (r < nrows)
        for (int j = 0; j < 4; ++j) {
          int col = wc * 64 + j * 16 + l16;
          OUT[(size_t)r * 128 + col] = f2b(acc[i][j][rr]);
        }
    }
}

// ---------------- edge stage (sorted order): MFMA GEMM + fused epilogue ----------------
// Attn dot computed from MFMA A-fragments in registers (wc==0 waves), quad-reduced
// via shfl_xor. Xs/Xd gathered as bf16.
__global__ __launch_bounds__(256)
void edge_fused(u16* HEF, const u16* ef, const u16* WeT, const u16* W_attn,
                const u16* b_edge, const u16* b_attn, const int* srcs, const int* dsts,
                const u16* Xs, const u16* Xd, const float* as_, const float* ad_,
                float* logit, int kc0) {
  __shared__ __align__(16) u16 Asm[128][40];
  __shared__ __align__(16) u16 Bsm[128][40];
  __shared__ float dotbuf[128];
  int blk = blockIdx.x, tid = threadIdx.x;
  int lane = tid & 63, wv = tid >> 6, wr = wv & 1, wc = wv >> 1;
  int q = lane >> 4, l16 = lane & 15;
  f32x4 acc[4][4];
  f32x4 zf = {0.f, 0.f, 0.f, 0.f};
  for (int i = 0; i < 4; ++i) for (int j = 0; j < 4; ++j) acc[i][j] = zf;
  float dp[4] = {0.f, 0.f, 0.f, 0.f};
  int arow = tid >> 1, ahalf = (tid & 1) * 16;
  long e0 = (long)blk * 128;
  const u16* wa = W_attn + 320;
  for (int kc = kc0; kc < 5; ++kc) {
    {
      long e = e0 + arow;
      const uint4* p = (kc < 4) ? (const uint4*)(HEF + e * 128 + kc * 32 + ahalf)
                                : (const uint4*)(ef + e * 32 + ahalf);
      uint4 v0 = p[0], v1 = p[1];
      *(uint4*)&Asm[arow][ahalf] = v0;
      *(uint4*)&Asm[arow][ahalf + 8] = v1;
    }
    {
      const uint4* p = (const uint4*)(WeT + arow * 160 + kc * 32 + ahalf);
      uint4 v0 = p[0], v1 = p[1];
      *(uint4*)&Bsm[arow][ahalf] = v0;
      *(uint4*)&Bsm[arow][ahalf + 8] = v1;
    }
    __syncthreads();
    bf16x8 af[4], bfr[4];
    for (int i = 0; i < 4; ++i) af[i] = *(const bf16x8*)&Asm[wr * 64 + i * 16 + l16][q * 8];
    for (int j = 0; j < 4; ++j) bfr[j] = *(const bf16x8*)&Bsm[wc * 64 + j * 16 + l16][q * 8];
    if (wc == 0) {
      bf16x8 wv8 = *(const bf16x8*)&wa[kc * 32 + q * 8];
      float wf[8];
      for (int j = 0; j < 8; ++j) wf[j] = b2f((u16)wv8[j]);
      for (int i = 0; i < 4; ++i)
        for (int j = 0; j < 8; ++j) dp[i] += b2f((u16)af[i][j]) * wf[j];
    }
    for (int i = 0; i < 4; ++i)
      for (int j = 0; j < 4; ++j)
        acc[i][j] = __builtin_amdgcn_mfma_f32_16x16x32_bf16(af[i], bfr[j], acc[i][j], 0, 0, 0);
    __syncthreads();
  }
  if (wc == 0) {
    for (int i = 0; i < 4; ++i) {
      dp[i] += __shfl_xor(dp[i], 16);
      dp[i] += __shfl_xor(dp[i], 32);
    }
    if (q == 0)
      for (int i = 0; i < 4; ++i) dotbuf[wr * 64 + i * 16 + l16] = dp[i];
  }
  __syncthreads();
  if (tid < 128) {
    long e = e0 + tid;
    logit[e] = dotbuf[tid] + as_[srcs[e]] + ad_[dsts[e]] + b2f(b_attn[0]);
  }
  for (int i = 0; i < 4; ++i)
    for (int rr = 0; rr < 4; ++rr) {
      int row = wr * 64 + i * 16 + q * 4 + rr;
      long e = e0 + row;
      int s = srcs[e], d = dsts[e];
      for (int j = 0; j < 4; ++j) {
        int col = wc * 64 + j * 16 + l16;
        float v = acc[i][j][rr] + b2f(Xs[(size_t)s * 128 + col]) + b2f(Xd[(size_t)d * 128 + col]) + b2f(b_edge[col]);
        HEF[e * 128 + col] = f2b(fmaxf(v, 0.f));
      }
    }
}

// ---------------- per-dst softmax + aggregation (sorted M: sequential reads) ----------------
__global__ __launch_bounds__(256)
void aggregate(const int* rowptr, const float* logit, const u16* M, u16* AGG, int nrows) {
  int gw = (blockIdx.x * blockDim.x + threadIdx.x) >> 6;
  int lane = threadIdx.x & 63;
  if (gw >= nrows) return;
  int beg = rowptr[gw], end = rowptr[gw + 1];
  float acc0 = 0.f, acc1 = 0.f;
  if (beg < end) {
    float mx = -1e30f;
    for (int j = beg + lane; j < end; j += 64) mx = fmaxf(mx, logit[j]);
    for (int off = 32; off > 0; off >>= 1) mx = fmaxf(mx, __shfl_xor(mx, off));
    float denom = 0.f;
    for (int j = beg; j < end; ++j) {
      float w = __expf(logit[j] - mx);
      denom += w;
      unsigned int mm = *(const unsigned int*)(M + (size_t)j * 128 + 2 * lane);
      acc0 += w * b2f((u16)(mm & 0xffffu));
      acc1 += w * b2f((u16)(mm >> 16));
    }
    float inv = 1.0f / fmaxf(denom, 1e-16f);
    acc0 *= inv; acc1 *= inv;
  }
  unsigned int out = (unsigned int)f2b(acc0) | ((unsigned int)f2b(acc1) << 16);
  *(unsigned int*)(AGG + (size_t)gw * 128 + 2 * lane) = out;
}

// ---------------- node update (MFMA, in-place HNF) ----------------
__global__ __launch_bounds__(256)
void node_update(u16* HNF, const u16* nf, const u16* AGG, const u16* WnuT,
                 const u16* b_node, int kc0, int nrows) {
  __shared__ __align__(16) u16 Asm[128][40];
  __shared__ __align__(16) u16 Bsm[128][40];
  int blk = blockIdx.x, tid = threadIdx.x;
  int lane = tid & 63, wv = tid >> 6, wr = wv & 1, wc = wv >> 1;
  f32x4 acc[4][4];
  f32x4 zf = {0.f, 0.f, 0.f, 0.f};
  for (int i = 0; i < 4; ++i) for (int j = 0; j < 4; ++j) acc[i][j] = zf;
  int arow = tid >> 1, ahalf = (tid & 1) * 16;
  int r0 = blk * 128;
  for (int kc = kc0; kc < 9; ++kc) {
    {
      int r = r0 + arow;
      uint4 v0 = make_uint4(0, 0, 0, 0), v1 = make_uint4(0, 0, 0, 0);
      if (r < nrows) {
        const u16* p;
        if (kc < 4) p = HNF + (size_t)r * 128 + kc * 32 + ahalf;
        else if (kc == 4) p = nf + (size_t)r * 32 + ahalf;
        else p = AGG + (size_t)r * 128 + (kc - 5) * 32 + ahalf;
        v0 = ((const uint4*)p)[0];
        v1 = ((const uint4*)p)[1];
      }
      *(uint4*)&Asm[arow][ahalf] = v0;
      *(uint4*)&Asm[arow][ahalf + 8] = v1;
    }
    {
      const uint4* p = (const uint4*)(WnuT + arow * 288 + kc * 32 + ahalf);
      uint4 v0 = p[0], v1 = p[1];
      *(uint4*)&Bsm[arow][ahalf] = v0;
      *(uint4*)&Bsm[arow][ahalf + 8] = v1;
    }
    __syncthreads();
    int q = lane >> 4, l16 = lane & 15;
    bf16x8 af[4], bfr[4];
    for (int i = 0; i < 4; ++i) af[i] = *(const bf16x8*)&Asm[wr * 64 + i * 16 + l16][q * 8];
    for (int j = 0; j < 4; ++j) bfr[j] = *(const bf16x8*)&Bsm[wc * 64 + j * 16 + l16][q * 8];
    for (int i = 0; i < 4; ++i)
      for (int j = 0; j < 4; ++j)
        acc[i][j] = __builtin_amdgcn_mfma_f32_16x16x32_bf16(af[i], bfr[j], acc[i][j], 0, 0, 0);
    __syncthreads();
  }
  int q = lane >> 4, l16 = lane & 15;
  for (int i = 0; i < 4; ++i)
    for (int rr = 0; rr < 4; ++rr) {
      int row = wr * 64 + i * 16 + q * 4 + rr;
      int r = r0 + row;
      if (r < nrows)
        for (int j = 0; j < 4; ++j) {
          int col = wc * 64 + j * 16 + l16;
          float v = acc[i][j][rr] + b2f(b_node[col]);
          HNF[(size_t)r * 128 + col] = f2b(fmaxf(v, 0.f));
        }
    }
}

// ---------------- output heads (MFMA, fp32 output, optional row remap) ----------------
__global__ __launch_bounds__(256)
void head_kernel(const u16* IN, const u16* WT, const u16* bias, float* OUT, long R,
                 const int* remap) {
  __shared__ __align__(16) u16 Asm[128][40];
  __shared__ __align__(16) u16 Bsm[32][40];
  int blk = blockIdx.x, tid = threadIdx.x;
  int lane = tid & 63, wv = tid >> 6;
  f32x4 acc[2][2];
  f32x4 zf = {0.f, 0.f, 0.f, 0.f};
  for (int i = 0; i < 2; ++i) for (int j = 0; j < 2; ++j) acc[i][j] = zf;
  int arow = tid >> 1, ahalf = (tid & 1) * 16;
  long r0 = (long)blk * 128;
  for (int kc = 0; kc < 4; ++kc) {
    {
      long r = r0 + arow;
      uint4 v0 = make_uint4(0, 0, 0, 0), v1 = make_uint4(0, 0, 0, 0);
      if (r < R) {
        const uint4* p = (const uint4*)(IN + r * 128 + kc * 32 + ahalf);
        v0 = p[0]; v1 = p[1];
      }
      *(uint4*)&Asm[arow][ahalf] = v0;
      *(uint4*)&Asm[arow][ahalf + 8] = v1;
    }
    if (tid < 64) {
      const uint4* p = (const uint4*)(WT + arow * 128 + kc * 32 + ahalf);
      uint4 v0 = p[0], v1 = p[1];
      *(uint4*)&Bsm[arow][ahalf] = v0;
      *(uint4*)&Bsm[arow][ahalf + 8] = v1;
    }
    __syncthreads();
    int q = lane >> 4, l16 = lane & 15;
    bf16x8 af[2], bfr[2];
    for (int i = 0; i < 2; ++i) af[i] = *(const bf16x8*)&Asm[wv * 32 + i * 16 + l16][q * 8];
    for (int j = 0; j < 2; ++j) bfr[j] = *(const bf16x8*)&Bsm[j * 16 + l16][q * 8];
    for (int i = 0; i < 2; ++i)
      for (int j = 0; j < 2; ++j)
        acc[i][j] = __builtin_amdgcn_mfma_f32_16x16x32_bf16(af[i], bfr[j], acc[i][j], 0, 0, 0);
    __syncthreads();
  }
  int q = lane >> 4, l16 = lane & 15;
  for (int i = 0; i < 2; ++i)
    for (int rr = 0; rr < 4; ++rr) {
      long r = r0 + wv * 32 + i * 16 + q * 4 + rr;
      if (r < R) {
        long ro = remap ? (long)remap[r] : r;
        for (int j = 0; j < 2; ++j) {
          int col = j * 16 + l16;
          OUT[ro * 32 + col] = acc[i][j][rr] + b2f(bias[col]);
        }
      }
    }
}

extern "C" void kernel_launch(void* const* d_in, const int* in_sizes, int n_in,
                              void* d_out, int out_size, void* d_ws, size_t ws_size,
                              hipStream_t stream) {
  const size_t REQUIRED = 160000000;
  if (ws_size < REQUIRED) return;

  const void* nf_r = d_in[0];
  const void* ef_r = d_in[1];
  const int* src = (const int*)d_in[2];
  const int* dst = (const int*)d_in[3];

  char* ws = (char*)d_ws;
  auto alloc = [&](size_t bytes) {
    char* p = ws;
    ws += (bytes + 255) & ~(size_t)255;
    return p;
  };
  u16* HEF = (u16*)alloc((size_t)GE * 128 * 2);
  u16* HNF = (u16*)alloc((size_t)GN * 128 * 2);
  u16* Xs = (u16*)alloc((size_t)GN * 128 * 2);
  u16* Xd = (u16*)alloc((size_t)GN * 128 * 2);
  float* as_ = (float*)alloc((size_t)GN * 4);
  float* ad_ = (float*)alloc((size_t)GN * 4);
  float* logit = (float*)alloc((size_t)GE * 4);
  int* rowptr = (int*)alloc((size_t)(GN + 1) * 4);
  int* cursor = (int*)alloc((size_t)GN * 4);
  int* eid = (int*)alloc((size_t)GE * 4);
  int* srcs = (int*)alloc((size_t)GE * 4);
  int* dsts = (int*)alloc((size_t)GE * 4);
  u16* WeT = (u16*)alloc(128 * 160 * 2);
  u16* WnpT = (u16*)alloc(256 * 160 * 2);
  u16* WnuT = (u16*)alloc(128 * 288 * 2);
  u16* WoN = (u16*)alloc(32 * 128 * 2);
  u16* WoE = (u16*)alloc(32 * 128 * 2);
  u16* nfc = (u16*)alloc((size_t)GN * 32 * 2);
  u16* efc = (u16*)alloc((size_t)GE * 32 * 2);
  u16* Wec = (u16*)alloc(480 * 128 * 2);
  u16* bec = (u16*)alloc(128 * 2);
  u16* Wac = (u16*)alloc(480 * 2);
  u16* bac = (u16*)alloc(2);
  u16* Wnc = (u16*)alloc(288 * 128 * 2);
  u16* bnc = (u16*)alloc(128 * 2);
  u16* Wnoc = (u16*)alloc(128 * 32 * 2);
  u16* bnoc = (u16*)alloc(32 * 2);
  u16* Weoc = (u16*)alloc(128 * 32 * 2);
  u16* beoc = (u16*)alloc(32 * 2);
  int* dflag = (int*)alloc(4);
  u16* AGG = Xs;  // overlay: Xs (bf16, 6.4MB) dead after edge stage; AGG consumed
                  // by node_update before next iter's node_proj rewrites Xs

  detect_dtype<<<1, 64, 0, stream>>>(nf_r, dflag);
  // CSR build first (gathers depend on eid)
  hipMemsetAsync(cursor, 0, (size_t)GN * 4, stream);
  hist_kernel<<<1563, 256, 0, stream>>>(dst, cursor, GE);
  scan_kernel<<<1, 256, 0, stream>>>(cursor, rowptr, GN);
  fill_kernel<<<1563, 256, 0, stream>>>(dst, cursor, eid, GE);

  convert_kernel<<<784, 256, 0, stream>>>(nf_r, nfc, (long)GN * 32, dflag);
  gather_ef<<<6250, 256, 0, stream>>>(ef_r, eid, efc, dflag);
  gather_meta<<<1563, 256, 0, stream>>>(src, dst, eid, srcs, dsts, GE);
  convert_kernel<<<240, 256, 0, stream>>>(d_in[4], Wec, 480 * 128, dflag);
  convert_kernel<<<1, 128, 0, stream>>>(d_in[5], bec, 128, dflag);
  convert_kernel<<<2, 256, 0, stream>>>(d_in[6], Wac, 480, dflag);
  convert_kernel<<<1, 64, 0, stream>>>(d_in[7], bac, 1, dflag);
  convert_kernel<<<144, 256, 0, stream>>>(d_in[8], Wnc, 288 * 128, dflag);
  convert_kernel<<<1, 128, 0, stream>>>(d_in[9], bnc, 128, dflag);
  convert_kernel<<<16, 256, 0, stream>>>(d_in[10], Wnoc, 128 * 32, dflag);
  convert_kernel<<<1, 64, 0, stream>>>(d_in[11], bnoc, 32, dflag);
  convert_kernel<<<16, 256, 0, stream>>>(d_in[12], Weoc, 128 * 32, dflag);
  convert_kernel<<<1, 64, 0, stream>>>(d_in[13], beoc, 32, dflag);
  prep_weights<<<128, 256, 0, stream>>>(Wec, Wnc, Wnoc, Weoc, WeT, WnpT, WnuT, WoN, WoE);

  for (int iter = 0; iter < 3; ++iter) {
    int kc0 = (iter == 0) ? 4 : 0;
    dim3 npgrid(NODE_BLKS, 2);
    node_proj<<<npgrid, 256, 0, stream>>>(HNF, nfc, WnpT, Wac, Xs, Xd, as_, ad_, kc0, GN);
    edge_fused<<<EDGE_BLKS, 256, 0, stream>>>(HEF, efc, WeT, Wac, bec, bac, srcs, dsts,
                                              Xs, Xd, as_, ad_, logit, kc0);
    aggregate<<<(GN + 3) / 4, 256, 0, stream>>>(rowptr, logit, HEF, AGG, GN);
    node_update<<<NODE_BLKS, 256, 0, stream>>>(HNF, nfc, AGG, WnuT, bnc, kc0, GN);
  }

  float* out_nf = (float*)d_out;
  float* out_ef = (float*)d_out + (size_t)GN * 32;
  head_kernel<<<NODE_BLKS, 256, 0, stream>>>(HNF, WoN, bnoc, out_nf, GN, nullptr);
  head_kernel<<<EDGE_BLKS, 256, 0, stream>>>(HEF, WoE, beoc, out_ef, GE, eid);
}